// Round 10
// baseline (32.469 us; speedup 1.0000x reference)
//
#include <hip/hip_runtime.h>
#include <math.h>

#define L_SEQ 4096    // sequence length L
#define SEG 512       // elements per segment (one wave per segment)
#define NSEG 8        // segments per sequence
#define NT 256        // threads per block (4 independent waves)
#define CHUNK 8       // elements per thread

struct M2 { float a00, a01, a10, a11; };

// max-plus 2x2 compose: C[s][t] = max_k(A[s][k] + B[k][t])
__device__ __forceinline__ M2 mpc(const M2& A, const M2& B) {
  M2 C;
  C.a00 = fmaxf(A.a00 + B.a00, A.a01 + B.a10);
  C.a01 = fmaxf(A.a00 + B.a01, A.a01 + B.a11);
  C.a10 = fmaxf(A.a10 + B.a00, A.a11 + B.a10);
  C.a11 = fmaxf(A.a10 + B.a01, A.a11 + B.a11);
  return C;
}

__device__ __forceinline__ M2 ldm(const float4& v) { return M2{v.x, v.y, v.z, v.w}; }
__device__ __forceinline__ float4 stm(const M2& m) { return make_float4(m.a00, m.a01, m.a10, m.a11); }

// DPP cross-lane fetch (VALU pipe). 0x110+N = row_shr:N,
// 0x142 = row_bcast:15, 0x143 = row_bcast:31.
template <int CTRL>
__device__ __forceinline__ float dppf(float x) {
  return __int_as_float(__builtin_amdgcn_update_dpp(
      0, __float_as_int(x), CTRL, 0xf, 0xf, true));
}
template <int CTRL>
__device__ __forceinline__ M2 dpp_fetch(const M2& x) {
  M2 r;
  r.a00 = dppf<CTRL>(x.a00); r.a01 = dppf<CTRL>(x.a01);
  r.a10 = dppf<CTRL>(x.a10); r.a11 = dppf<CTRL>(x.a11);
  return r;
}

// Build the 8-bit-pattern LUT in LDS (SoA). 2 barriers; then waves independent.
__device__ __forceinline__ void build_lut(
    int t, float P, float hb0, float hb1, float4* T4s,
    float* T8a, float* T8b, float* T8c, float* T8d) {
  if (t < 16) {
    float u0 = (t & 1) ? hb1 : hb0;
    M2 Tt{P - u0, -u0 - P, u0 - P, u0 + P};
    #pragma unroll
    for (int k = 1; k < 4; ++k) {
      float uk = ((t >> k) & 1) ? hb1 : hb0;
      M2 Ek{P - uk, -uk - P, uk - P, uk + P};
      Tt = mpc(Tt, Ek);
    }
    T4s[t] = stm(Tt);
  }
  __syncthreads();
  {  // one entry per thread (NT == 256)
    M2 M = mpc(ldm(T4s[t & 15]), ldm(T4s[(t >> 4) & 15]));
    T8a[t] = M.a00; T8b[t] = M.a01; T8c[t] = M.a10; T8d[t] = M.a11;
  }
  __syncthreads();
}

// Dual inclusive Hillis-Steele scan over the wave via DPP.
__device__ __forceinline__ void dpp_dual_scan(M2& T, M2& Rv, int lane) {
  M2 f, g;
  f = dpp_fetch<0x111>(T); g = dpp_fetch<0x111>(Rv);           // row_shr:1
  if ((lane & 15) >= 1) { T = mpc(f, T); Rv = mpc(g, Rv); }
  f = dpp_fetch<0x112>(T); g = dpp_fetch<0x112>(Rv);           // row_shr:2
  if ((lane & 15) >= 2) { T = mpc(f, T); Rv = mpc(g, Rv); }
  f = dpp_fetch<0x114>(T); g = dpp_fetch<0x114>(Rv);           // row_shr:4
  if ((lane & 15) >= 4) { T = mpc(f, T); Rv = mpc(g, Rv); }
  f = dpp_fetch<0x118>(T); g = dpp_fetch<0x118>(Rv);           // row_shr:8
  if ((lane & 15) >= 8) { T = mpc(f, T); Rv = mpc(g, Rv); }
  f = dpp_fetch<0x142>(T); g = dpp_fetch<0x142>(Rv);           // row_bcast:15
  if (lane & 16)        { T = mpc(f, T); Rv = mpc(g, Rv); }
  f = dpp_fetch<0x143>(T); g = dpp_fetch<0x143>(Rv);           // row_bcast:31
  if (lane >= 32)       { T = mpc(f, T); Rv = mpc(g, Rv); }
}

// ---------------- Kernel A: per-segment fwd/bwd totals -> ws ----------------
__global__ __launch_bounds__(NT, 8) void seg_totals_kernel(
    const float* __restrict__ jp, const float* __restrict__ bp,
    const int* __restrict__ obs, float4* __restrict__ ws) {
  __shared__ float4 T4s[16];
  __shared__ float T8a[256], T8b[256], T8c[256], T8d[256];

  const int t = threadIdx.x;
  const int lane = t & 63;
  const long g = (long)blockIdx.x * (NT / 64) + (t >> 6);   // global segment id

  const float P   = 0.25f * jp[0];
  const float hb0 = 0.5f * bp[0];
  const float hb1 = 0.5f * bp[1];

  const int4* rowp = (const int4*)(obs + g * SEG + lane * CHUNK);
  int4 q0 = rowp[0], q1 = rowp[1];

  build_lut(t, P, hb0, hb1, T4s, T8a, T8b, T8c, T8d);

  const unsigned m =
      (unsigned)(q0.x & 1)       | (unsigned)(q0.y & 1) << 1 |
      (unsigned)(q0.z & 1) << 2  | (unsigned)(q0.w & 1) << 3 |
      (unsigned)(q1.x & 1) << 4  | (unsigned)(q1.y & 1) << 5 |
      (unsigned)(q1.z & 1) << 6  | (unsigned)(q1.w & 1) << 7;
  const unsigned mrev = (unsigned)__shfl((int)m, 63 - lane);
  const unsigned r = __brev(mrev) >> 24;
  M2 T {T8a[m], T8b[m], T8c[m], T8d[m]};   // fwd chunk transform
  M2 Rv{T8a[r], T8b[r], T8c[r], T8d[r]};   // bwd transform of mirrored chunk

  dpp_dual_scan(T, Rv, lane);

  if (lane == 63) {            // segment totals (fwd, bwd)
    ws[2 * g]     = stm(T);
    ws[2 * g + 1] = stm(Rv);
  }
}

// ---------------- Kernel B: full messages + fused output ----------------
__global__ __launch_bounds__(NT, 8) void chain_out_kernel(
    const float* __restrict__ jp, const float* __restrict__ bp,
    const int* __restrict__ obs, const float4* __restrict__ ws,
    float* __restrict__ out) {
  __shared__ float4 T4s[16];
  __shared__ float T8a[256], T8b[256], T8c[256], T8d[256];

  const int t = threadIdx.x;
  const int lane = t & 63;
  const long g = (long)blockIdx.x * (NT / 64) + (t >> 6);   // global segment id
  const long seq = g >> 3;
  const int  seg = (int)(g & 7);

  const float P   = 0.25f * jp[0];
  const float hb0 = 0.5f * bp[0];
  const float hb1 = 0.5f * bp[1];

  const int4* rowp = (const int4*)(obs + g * SEG + lane * CHUNK);
  int4 q0 = rowp[0], q1 = rowp[1];

  build_lut(t, P, hb0, hb1, T4s, T8a, T8b, T8c, T8d);

  const unsigned m =
      (unsigned)(q0.x & 1)       | (unsigned)(q0.y & 1) << 1 |
      (unsigned)(q0.z & 1) << 2  | (unsigned)(q0.w & 1) << 3 |
      (unsigned)(q1.x & 1) << 4  | (unsigned)(q1.y & 1) << 5 |
      (unsigned)(q1.z & 1) << 6  | (unsigned)(q1.w & 1) << 7;
  const unsigned mrev = (unsigned)__shfl((int)m, 63 - lane);
  const unsigned r = __brev(mrev) >> 24;
  M2 T {T8a[m], T8b[m], T8c[m], T8d[m]};
  M2 Rv{T8a[r], T8b[r], T8c[r], T8d[r]};

  dpp_dual_scan(T, Rv, lane);

  // intra-wave exclusive versions (shift by 1; identity at lane 0)
  M2 EF{__shfl_up(T.a00, 1), __shfl_up(T.a01, 1),
        __shfl_up(T.a10, 1), __shfl_up(T.a11, 1)};
  M2 EB{__shfl_up(Rv.a00, 1), __shfl_up(Rv.a01, 1),
        __shfl_up(Rv.a10, 1), __shfl_up(Rv.a11, 1)};
  if (lane == 0) {
    EF.a00 = 0.f; EF.a01 = -INFINITY; EF.a10 = -INFINITY; EF.a11 = 0.f;
    EB.a00 = 0.f; EB.a01 = -INFINITY; EB.a10 = -INFINITY; EB.a11 = 0.f;
  }

  // tail: compose other segments' totals from ws (L2-hot broadcast lines)
  M2 GF = EF, GB = EB;
  for (int s = seg - 1; s >= 0; --s) GF = mpc(ldm(ws[2 * (seq * NSEG + s)]), GF);
  for (int s = seg + 1; s < NSEG; ++s) GB = mpc(ldm(ws[2 * (seq * NSEG + s) + 1]), GB);

  float fm0 = fmaxf(GF.a00, GF.a10), fm1 = fmaxf(GF.a01, GF.a11);
  const float bv0 = fmaxf(GB.a00, GB.a10), bv1 = fmaxf(GB.a01, GB.a11);
  float bm0 = __shfl(bv0, 63 - lane);   // bwd message back to natural lane
  float bm1 = __shfl(bv1, 63 - lane);

  // fwd replay: o = phi + fwd
  float o0[CHUNK], o1[CHUNK];
  #pragma unroll
  for (int e = 0; e < CHUNK; ++e) {
    float u = ((m >> e) & 1) ? hb1 : hb0;
    float x = fm0 - u, y = fm1 + u;
    o0[e] = x; o1[e] = y;
    fm0 = fmaxf(x + P, y - P);
    fm1 = fmaxf(x - P, y + P);
  }
  // bwd replay: add bwd message (right->left)
  #pragma unroll
  for (int e = CHUNK - 1; e >= 0; --e) {
    float u = ((m >> e) & 1) ? hb1 : hb0;
    o0[e] += bm0; o1[e] += bm1;
    float x = bm0 - u, y = bm1 + u;
    bm0 = fmaxf(x + P, y - P);
    bm1 = fmaxf(x - P, y + P);
  }

  // store: contiguous 8 floats per state row (coalesced float4s)
  const long base = (long)seg * SEG + lane * CHUNK;
  float* r0 = out + seq * (2L * L_SEQ) + base;   // out[seq][0][base..]
  float* r1 = r0 + L_SEQ;                        // out[seq][1][base..]
  ((float4*)r0)[0] = make_float4(o0[0], o0[1], o0[2], o0[3]);
  ((float4*)r0)[1] = make_float4(o0[4], o0[5], o0[6], o0[7]);
  ((float4*)r1)[0] = make_float4(o1[0], o1[1], o1[2], o1[3]);
  ((float4*)r1)[1] = make_float4(o1[4], o1[5], o1[6], o1[7]);
}

extern "C" void kernel_launch(void* const* d_in, const int* in_sizes, int n_in,
                              void* d_out, int out_size, void* d_ws, size_t ws_size,
                              hipStream_t stream) {
  const float* jp  = (const float*)d_in[0];
  const float* bp  = (const float*)d_in[1];
  const int*   obs = (const int*)d_in[2];
  float* out = (float*)d_out;
  float4* ws = (float4*)d_ws;                    // 16384 segs x 2 float4 = 512 KB
  const int B = in_sizes[2] / L_SEQ;             // 2048
  const int nseg_total = B * NSEG;               // 16384 segments
  const int blocks = nseg_total / (NT / 64);     // 4096 blocks (4 waves each)
  seg_totals_kernel<<<blocks, NT, 0, stream>>>(jp, bp, obs, ws);
  chain_out_kernel<<<blocks, NT, 0, stream>>>(jp, bp, obs, ws, out);
}

// Round 11
// 23.210 us; speedup vs baseline: 1.3989x; 1.3989x over previous
//
#include <hip/hip_runtime.h>
#include <math.h>

#define L_SEQ 4096   // sequence length L
#define NT 512       // threads per block (one block per sequence)
#define CHUNK 8      // elements per thread
#define NW (NT/64)   // waves per block (8)

typedef float f2 __attribute__((ext_vector_type(2)));

__device__ __forceinline__ f2 mkf2(float a, float b) { f2 r; r.x = a; r.y = b; return r; }
__device__ __forceinline__ f2 max2(f2 a, f2 b) { return mkf2(fmaxf(a.x, b.x), fmaxf(a.y, b.y)); }
__device__ __forceinline__ float hmax(f2 v) { return fmaxf(v.x, v.y); }

struct M2 { f2 r0, r1; };   // rows: r0=(a00,a01), r1=(a10,a11)

// max-plus 2x2 compose: C[s][t] = max_k(A[s][k] + B[k][t])  (packed rows)
__device__ __forceinline__ M2 mpc(const M2& A, const M2& B) {
  M2 C;
  C.r0 = max2(mkf2(A.r0.x, A.r0.x) + B.r0, mkf2(A.r0.y, A.r0.y) + B.r1);
  C.r1 = max2(mkf2(A.r1.x, A.r1.x) + B.r0, mkf2(A.r1.y, A.r1.y) + B.r1);
  return C;
}
// row-vector max-plus apply: r[t] = max_s(v[s] + M[s][t])
__device__ __forceinline__ f2 mapply(f2 v, const M2& M) {
  return max2(mkf2(v.x, v.x) + M.r0, mkf2(v.y, v.y) + M.r1);
}
__device__ __forceinline__ f2 colmax(const M2& M) { return max2(M.r0, M.r1); }

__device__ __forceinline__ M2 ld4(float4 v) { M2 M; M.r0 = mkf2(v.x, v.y); M.r1 = mkf2(v.z, v.w); return M; }
__device__ __forceinline__ float4 st4(const M2& M) { return make_float4(M.r0.x, M.r0.y, M.r1.x, M.r1.y); }

// DPP cross-lane fetch (VALU pipe). 0x110+N = row_shr:N, 0x142 = row_bcast:15,
// 0x143 = row_bcast:31, 0x138 = wave_shr:1 (crosses rows, lane0 -> 0).
template <int CTRL>
__device__ __forceinline__ float dppf(float x) {
  return __int_as_float(__builtin_amdgcn_update_dpp(
      0, __float_as_int(x), CTRL, 0xf, 0xf, true));
}
template <int CTRL>
__device__ __forceinline__ f2 dpp2(f2 x) { return mkf2(dppf<CTRL>(x.x), dppf<CTRL>(x.y)); }
template <int CTRL>
__device__ __forceinline__ M2 dpp_fetch(const M2& x) {
  M2 r; r.r0 = dpp2<CTRL>(x.r0); r.r1 = dpp2<CTRL>(x.r1); return r;
}
__device__ __forceinline__ float rdl(float x, int l) {
  return __int_as_float(__builtin_amdgcn_readlane(__float_as_int(x), l));
}

__global__ __launch_bounds__(NT, 8) void chain_fb_kernel(
    const float* __restrict__ jp, const float* __restrict__ bp,
    const int* __restrict__ obs, float* __restrict__ out) {
  __shared__ float4 T4s[16];             // 4-bit-pattern transforms
  __shared__ f2 T8r0[256], T8r1[256];    // 8-bit LUT rows (4 KB)
  __shared__ float4 wtf[NW];             // fwd wave totals
  __shared__ float4 wtbr[NW];            // bwd wave totals, REVERSED slot order

  const int t = threadIdx.x;
  const int lane = t & 63;
  const int w = t >> 6;
  const long b = blockIdx.x;

  const float P   = 0.25f * jp[0];   // psi = [[P,-P],[-P,P]]
  const float hb0 = 0.5f * bp[0];    // u_i = 0.5*b[obs_i]; phi_i = (-u, +u)
  const float hb1 = 0.5f * bp[1];

  // ---- issue obs loads first (latency hidden under LUT build)
  const int4* rowp = (const int4*)(obs + b * L_SEQ + (long)t * CHUNK);
  int4 q0 = rowp[0], q1 = rowp[1];

  // ---- build LUT: pattern p -> E(p0)(*)E(p1)(*)... (bit 0 = earliest elem)
  //      E(u): r0 = (P-u, -u-P), r1 = (u-P, u+P)
  if (t < 16) {
    float u0 = (t & 1) ? hb1 : hb0;
    M2 Tt; Tt.r0 = mkf2(P - u0, -u0 - P); Tt.r1 = mkf2(u0 - P, u0 + P);
    #pragma unroll
    for (int k = 1; k < 4; ++k) {
      float uk = ((t >> k) & 1) ? hb1 : hb0;
      M2 Ek; Ek.r0 = mkf2(P - uk, -uk - P); Ek.r1 = mkf2(uk - P, uk + P);
      Tt = mpc(Tt, Ek);
    }
    T4s[t] = st4(Tt);
  }
  __syncthreads();
  if (t < 256) {  // T8[p] = T4[p&15] (*) T4[p>>4]
    M2 M = mpc(ld4(T4s[t & 15]), ld4(T4s[(t >> 4) & 15]));
    T8r0[t] = M.r0; T8r1[t] = M.r1;
  }
  // pack obs bit mask while the barrier drains
  const unsigned m =
      (unsigned)(q0.x & 1)       | (unsigned)(q0.y & 1) << 1 |
      (unsigned)(q0.z & 1) << 2  | (unsigned)(q0.w & 1) << 3 |
      (unsigned)(q1.x & 1) << 4  | (unsigned)(q1.y & 1) << 5 |
      (unsigned)(q1.z & 1) << 6  | (unsigned)(q1.w & 1) << 7;
  __syncthreads();

  // ---- chunk transforms: fwd for own chunk; bwd for MIRRORED chunk (v-space)
  const unsigned mrev = (unsigned)__shfl((int)m, 63 - lane);
  const unsigned r = __brev(mrev) >> 24;
  M2 T;  T.r0  = T8r0[m]; T.r1  = T8r1[m];   // fwd: E(u0)(*)...(*)E(u7)
  M2 Rv; Rv.r0 = T8r0[r]; Rv.r1 = T8r1[r];   // bwd of chunk 63-lane

  // ---- dual Hillis-Steele inclusive scans via DPP (VALU pipe)
  {
    M2 f, g;
    f = dpp_fetch<0x111>(T); g = dpp_fetch<0x111>(Rv);           // row_shr:1
    if ((lane & 15) >= 1) { T = mpc(f, T); Rv = mpc(g, Rv); }
    f = dpp_fetch<0x112>(T); g = dpp_fetch<0x112>(Rv);           // row_shr:2
    if ((lane & 15) >= 2) { T = mpc(f, T); Rv = mpc(g, Rv); }
    f = dpp_fetch<0x114>(T); g = dpp_fetch<0x114>(Rv);           // row_shr:4
    if ((lane & 15) >= 4) { T = mpc(f, T); Rv = mpc(g, Rv); }
    f = dpp_fetch<0x118>(T); g = dpp_fetch<0x118>(Rv);           // row_shr:8
    if ((lane & 15) >= 8) { T = mpc(f, T); Rv = mpc(g, Rv); }
    f = dpp_fetch<0x142>(T); g = dpp_fetch<0x142>(Rv);           // row_bcast:15
    if (lane & 16)        { T = mpc(f, T); Rv = mpc(g, Rv); }
    f = dpp_fetch<0x143>(T); g = dpp_fetch<0x143>(Rv);           // row_bcast:31
    if (lane >= 32)       { T = mpc(f, T); Rv = mpc(g, Rv); }
  }
  if (lane == 63) { wtf[w] = st4(T); wtbr[7 - w] = st4(Rv); }

  __syncthreads();  // wave totals visible

  // ---- cross-wave tail: 8-lane DPP mini-scan of wave totals (lanes 0-7
  //      valid; replicas in higher lanes are garbage and unused), then
  //      wave-uniform message via readlane.
  M2 Xf = ld4(wtf[lane & 7]);
  M2 Xb = ld4(wtbr[lane & 7]);
  {
    M2 f, g;
    f = dpp_fetch<0x111>(Xf); g = dpp_fetch<0x111>(Xb);
    if ((lane & 15) >= 1) { Xf = mpc(f, Xf); Xb = mpc(g, Xb); }
    f = dpp_fetch<0x112>(Xf); g = dpp_fetch<0x112>(Xb);
    if ((lane & 15) >= 2) { Xf = mpc(f, Xf); Xb = mpc(g, Xb); }
    f = dpp_fetch<0x114>(Xf); g = dpp_fetch<0x114>(Xb);
    if ((lane & 15) >= 4) { Xf = mpc(f, Xf); Xb = mpc(g, Xb); }
  }
  const f2 Vf = colmax(Xf);   // Vf at lane l = msg after waves 0..l
  const f2 Vb = colmax(Xb);   // Vb at lane l = msg after waves 7..7-l (bwd)

  f2 v, vb;   // wave-incoming messages (wave-uniform)
  if (w > 0) v = mkf2(rdl(Vf.x, w - 1), rdl(Vf.y, w - 1));
  else       v = mkf2(0.f, 0.f);
  if (w < 7) vb = mkf2(rdl(Vb.x, 6 - w), rdl(Vb.y, 6 - w));
  else       vb = mkf2(0.f, 0.f);

  // per-lane exclusive messages: apply v through own inclusive scan, then
  // shift down one lane (wave_shr:1 crosses rows); lane 0 = wave-incoming.
  f2 wv  = mapply(v,  T);
  f2 wvb = mapply(vb, Rv);
  f2 fm  = dpp2<0x138>(wv);
  f2 bmv = dpp2<0x138>(wvb);
  if (lane == 0) { fm = v; bmv = vb; }
  // bwd message computed at v-lane (63-lane): mirror back
  f2 bm = mkf2(__shfl(bmv.x, 63 - lane), __shfl(bmv.y, 63 - lane));

  // ---- replay (packed): xy = (phi0+msg0, phi1+msg1)
  const f2 pp  = mkf2(P, -P), pm = mkf2(-P, P);
  const f2 uvl = mkf2(-hb0, hb0), uvh = mkf2(-hb1, hb1);
  f2 o[CHUNK];
  #pragma unroll
  for (int e = 0; e < CHUNK; ++e) {
    f2 uv = ((m >> e) & 1) ? uvh : uvl;
    f2 xy = fm + uv;
    o[e] = xy;
    fm = mkf2(hmax(xy + pp), hmax(xy + pm));
  }
  #pragma unroll
  for (int e = CHUNK - 1; e >= 0; --e) {
    f2 uv = ((m >> e) & 1) ? uvh : uvl;
    o[e] += bm;
    f2 xy = bm + uv;
    bm = mkf2(hmax(xy + pp), hmax(xy + pm));
  }

  // ---- store: contiguous 8 floats per state row (coalesced float4s)
  const long base = (long)t * CHUNK;
  float* r0 = out + b * (2L * L_SEQ) + base;   // out[b][0][base..]
  float* r1 = r0 + L_SEQ;                      // out[b][1][base..]
  ((float4*)r0)[0] = make_float4(o[0].x, o[1].x, o[2].x, o[3].x);
  ((float4*)r0)[1] = make_float4(o[4].x, o[5].x, o[6].x, o[7].x);
  ((float4*)r1)[0] = make_float4(o[0].y, o[1].y, o[2].y, o[3].y);
  ((float4*)r1)[1] = make_float4(o[4].y, o[5].y, o[6].y, o[7].y);
}

extern "C" void kernel_launch(void* const* d_in, const int* in_sizes, int n_in,
                              void* d_out, int out_size, void* d_ws, size_t ws_size,
                              hipStream_t stream) {
  const float* jp  = (const float*)d_in[0];
  const float* bp  = (const float*)d_in[1];
  const int*   obs = (const int*)d_in[2];
  float* out = (float*)d_out;
  const int B = in_sizes[2] / L_SEQ;   // 2048
  chain_fb_kernel<<<B, NT, 0, stream>>>(jp, bp, obs, out);
}